// Round 8
// baseline (131.079 us; speedup 1.0000x reference)
//
#include <hip/hip_runtime.h>
#include <hip/hip_fp16.h>

// L=8 layers, H=512, K=16 links, N_IN=512, B=8192; out = last 512 cols (fp32).
#define LAYERS 8
#define H      512
#define K      16
#define N_IN   512
#define BATCH  8192
#define R      4      // batch rows per block; 4 x f16 = 8 B -> one ds_read_b64 per gather
#define NT     512    // 8 waves/block; 32 KB LDS -> 4 blocks/CU -> 32 waves/CU (full)
// Layer l gathers from cols [0, 512+512*l); max l=7 -> cols < 4096. Layer 7's
// output is never gathered -> straight to global. LDS = 4096*8 B = 32 KB.
#define LDS_COLS 4096

// History:
//  R3/R4: NT=1024 spills regardless of __launch_bounds__. Stay at NT=512.
//  R5/R7: bank-group sort+stagger prep: conflicts only -12%. Post-hoc model
//    fix: ~7 of the 8.3 counted conflict cycles/read are the irreducible
//    1024B/128B-per-cyc serialization of a wave b128 -- there was almost
//    nothing reducible. Prep dispatch also cost ~10us e2e. Reverted.
//  R8/R9/R10: deeper per-wave read queues (rolling buffer, burst-8+
//    sched_barrier) all LOST to the compiler's simple schedule even with no
//    spill (R10: VGPR 76, clean, 57-60us vs R0's 50). ILP path exhausted.
//  R11 (this): counters say nothing saturates (LDS ~45%, VALU ~38%, occ 34%)
//    -> latency-bound with 8 barriers/block and only 2 independent blocks/CU
//    (64KB LDS cap). Trade: R=8 -> R=4 (32KB LDS) -> 4 blocks/CU, 32 waves/CU.
//    b64 gathers are ~15% worse per byte, but 2x block-level overlap hides
//    barrier drains + param loads. B-prefetch dropped (TLP replaces ILP) to
//    fit the 64-VGPR cap of (NT,4) [R9: 2nd arg acts as min-blocks/CU here].
//    Tripwire: WRITE_SIZE >> 16.4MB = spill -> revert to R=8 config.

__global__ __launch_bounds__(NT, 4)
void ffn_fused_kernel(const float* __restrict__ x,
                      const int*   __restrict__ link_idx,
                      const float* __restrict__ weights,
                      const float* __restrict__ bias,
                      float*       __restrict__ out)
{
    // vals[c*R + r] = f16 value of column c, block batch-row r.
    __shared__ __align__(16) __half vals[LDS_COLS * R];   // 32768 B

    const int tid  = threadIdx.x;
    const int row0 = blockIdx.x * R;

    // ---- Stage x rows into LDS as f16 (each thread owns one column) ----
    {
        const int c = tid;                     // NT == N_IN == 512
        float v[R];
        #pragma unroll
        for (int r = 0; r < R; ++r)
            v[r] = x[(row0 + r) * N_IN + c];   // coalesced per r
        __half2 p[R / 2];
        #pragma unroll
        for (int r = 0; r < R / 2; ++r)
            p[r] = __floats2half2_rn(v[2 * r], v[2 * r + 1]);
        *(uint2*)&vals[c * R] = *(const uint2*)p;   // one ds_write_b64, contiguous
    }

    __syncthreads();

    // ---- Layers (each thread owns one h; 4 batch rows in registers) ----
    #pragma unroll
    for (int l = 0; l < LAYERS; ++l) {
        // Per-layer param load, no prefetch: at 32 waves/CU the L2 latency is
        // hidden by TLP, and dropping the B-copy saves ~33 VGPR (fits the
        // 64-reg cap without spilling).
        int idxA[K]; float wA[K];
        {
            const int base = (l * H + tid) * K;
            #pragma unroll
            for (int q = 0; q < 4; ++q) {
                *(int4*)  &idxA[4 * q] = ((const int4*)  (link_idx + base))[q];
                *(float4*)&wA  [4 * q] = ((const float4*)(weights  + base))[q];
            }
            #pragma unroll
            for (int k = 0; k < K; ++k) idxA[k] <<= 3;   // byte offsets (R=4 -> x8)
        }
        const float bA = bias[l * H + tid];

        float acc[R];
        #pragma unroll
        for (int r = 0; r < R; ++r) acc[r] = bA;

        // Simple sequential gather loop -- the schedule the compiler handled
        // best across R0/R8/R9/R10. One ds_read_b64 = 4 rows of one column.
        #pragma unroll
        for (int k = 0; k < K; ++k) {
            const uint2 g = *(const uint2*)((const char*)vals + idxA[k]);
            const __half2* hp = (const __half2*)&g;
            const float wk = wA[k];
            #pragma unroll
            for (int r = 0; r < R / 2; ++r) {
                const float2 f = __half22float2(hp[r]);   // folds into v_fma_mix_f32
                acc[2 * r]     = fmaf(f.x, wk, acc[2 * r]);
                acc[2 * r + 1] = fmaf(f.y, wk, acc[2 * r + 1]);
            }
        }

        // sigmoid via v_rcp_f32 (~1 ulp) instead of the ~10-instr exact divide
        #pragma unroll
        for (int r = 0; r < R; ++r)
            acc[r] = __builtin_amdgcn_rcpf(1.0f + __expf(-acc[r]));

        if (l < LAYERS - 1) {
            // write col (N_IN + l*H + tid): disjoint from this layer's read
            // range [0, 512+512l) -> single barrier per layer suffices.
            __half2 p[R / 2];
            #pragma unroll
            for (int r = 0; r < R / 2; ++r)
                p[r] = __floats2half2_rn(acc[2 * r], acc[2 * r + 1]);
            *(uint2*)&vals[(N_IN + l * H + tid) * R] = *(const uint2*)p;
            __syncthreads();
        } else {
            // final layer: coalesced fp32 stores (lanes -> consecutive h)
            #pragma unroll
            for (int r = 0; r < R; ++r)
                out[(row0 + r) * H + tid] = acc[r];
        }
    }
}

extern "C" void kernel_launch(void* const* d_in, const int* in_sizes, int n_in,
                              void* d_out, int out_size, void* d_ws, size_t ws_size,
                              hipStream_t stream) {
    const float* x        = (const float*)d_in[0];
    const int*   link_idx = (const int*)  d_in[1];
    const float* weights  = (const float*)d_in[2];
    const float* bias     = (const float*)d_in[3];
    float*       out      = (float*)d_out;

    ffn_fused_kernel<<<dim3(BATCH / R), dim3(NT), 0, stream>>>(x, link_idx, weights, bias, out);
}

// Round 9
// 123.409 us; speedup vs baseline: 1.0622x; 1.0622x over previous
//
#include <hip/hip_runtime.h>
#include <hip/hip_fp16.h>

// L=8 layers, H=512, K=16 links, N_IN=512, B=8192; out = last 512 cols (fp32).
#define LAYERS 8
#define H      512
#define K      16
#define N_IN   512
#define BATCH  8192
#define R      8      // rows per block: 4 in group A + 4 in group B
#define NT     512    // 8 waves/block; 64 KB LDS -> 2 blocks/CU -> 16 waves/CU
// Layer l gathers from cols [0, 512+512*l); max l=7 -> cols < 4096.
// LDS: two 32KB halves. A half: vals[c*8 .. c*8+7] = rows 0-3 of col c (f16).
// B half: same layout at byte offset 32768 = rows 4-7.
#define LDS_COLS 4096
#define HALF_OFS 32768

// History:
//  R3/R4: NT=1024 spills regardless of __launch_bounds__. Stay at NT=512.
//  R5/R7: bank-group sort+stagger prep: conflicts only -12% (dynamic arbiter;
//    static lane perms can't debias); prep dispatch cost ~10us e2e. BUT the
//    sorted kernel's dispatches were the fastest seen (48.1-48.6us) -- conflict
//    cycles do convert to time ~1:1.
//  R8/R9/R10: deeper same-chain read queues (rolling buffer, burst-8 +
//    sched_barrier) all regressed even with no spill (R10: VGPR 76 clean,
//    57-60us). Single-chain ILP exhausted.
//  R11: R=4, 2x occupancy (72%): 74us. Confounded (2x param traffic, no
//    prefetch) but kills the pure-TLP theory.
//  R12 (this): R0's 50us = 34us LDS + 20us VALU = serial SUM, not max ->
//    barrier-phase-locked convoy; waves stall on in-order lgkmcnt with no
//    ready VALU work. Fix at constant economics: split rows into A/B groups
//    in the two 32KB LDS halves; each gather = 2x ds_read_b64 (same vaddr,
//    offset:32768) feeding 2 independent acc chains -> stall coverage.
//    Blocks/params/prefetch/occupancy identical to R0.
//    Tripwire: WRITE_SIZE >> 16.4MB = spill -> revert to R0 exact.

__global__ __launch_bounds__(NT, 2)
void ffn_fused_kernel(const float* __restrict__ x,
                      const int*   __restrict__ link_idx,
                      const float* __restrict__ weights,
                      const float* __restrict__ bias,
                      float*       __restrict__ out)
{
    __shared__ __align__(16) __half vals[2 * LDS_COLS * 4];   // 65536 B

    const int tid  = threadIdx.x;
    const int row0 = blockIdx.x * R;

    // ---- Stage x rows into LDS as f16 (each thread owns one column) ----
    {
        const int c = tid;                     // NT == N_IN == 512
        float v[R];
        #pragma unroll
        for (int r = 0; r < R; ++r)
            v[r] = x[(row0 + r) * N_IN + c];   // coalesced per r
        __half2 pa[2], pb[2];
        #pragma unroll
        for (int j = 0; j < 2; ++j) {
            pa[j] = __floats2half2_rn(v[2 * j],     v[2 * j + 1]);      // rows 0-3
            pb[j] = __floats2half2_rn(v[2 * j + 4], v[2 * j + 5]);      // rows 4-7
        }
        char* bp = (char*)vals + c * 8;
        *(uint2*)bp              = *(const uint2*)pa;   // ds_write_b64 (A half)
        *(uint2*)(bp + HALF_OFS) = *(const uint2*)pb;   // ds_write_b64 (B half)
    }

    // ---- Preload layer-0 params while LDS staging drains (before barrier) ----
    int   idxA[K]; float wA[K]; float bA;
    {
        const int base = tid * K;              // l=0, h=tid
        #pragma unroll
        for (int q = 0; q < 4; ++q) {
            *(int4*)  &idxA[4 * q] = ((const int4*)  (link_idx + base))[q];
            *(float4*)&wA  [4 * q] = ((const float4*)(weights  + base))[q];
        }
        #pragma unroll
        for (int k = 0; k < K; ++k) idxA[k] <<= 3;   // byte offset (8 B/col/half)
        bA = bias[tid];
    }

    __syncthreads();

    // ---- Layers (each thread owns one h; 4+4 batch rows in registers) ----
    #pragma unroll
    for (int l = 0; l < LAYERS; ++l) {
        // Prefetch next layer's params under this layer's gather/FMA work.
        int idxB[K]; float wB[K]; float bB = 0.0f;
        if (l < LAYERS - 1) {
            const int nb = ((l + 1) * H + tid) * K;
            #pragma unroll
            for (int q = 0; q < 4; ++q) {
                *(int4*)  &idxB[4 * q] = ((const int4*)  (link_idx + nb))[q];
                *(float4*)&wB  [4 * q] = ((const float4*)(weights  + nb))[q];
            }
            #pragma unroll
            for (int k = 0; k < K; ++k) idxB[k] <<= 3;
            bB = bias[(l + 1) * H + tid];
        }

        float acc[R];   // [0..3] = group A rows, [4..7] = group B rows
        #pragma unroll
        for (int r = 0; r < R; ++r) acc[r] = bA;

        // Two independent dep chains per k: A-read/A-fma and B-read/B-fma.
        // Same vaddr, B at +32768 (16-bit ds offset; same bank, different row
        // -> 2-way pairing is free per m136). While one chain waits on
        // lgkmcnt, the other chain's FMAs are ready -> covers the stall.
        #pragma unroll
        for (int k = 0; k < K; ++k) {
            const char* bp = (const char*)vals + idxA[k];
            const uint2 ga = *(const uint2*)bp;               // rows 0-3
            const uint2 gb = *(const uint2*)(bp + HALF_OFS);  // rows 4-7
            const __half2* ha = (const __half2*)&ga;
            const __half2* hb = (const __half2*)&gb;
            const float wk = wA[k];
            #pragma unroll
            for (int j = 0; j < 2; ++j) {
                const float2 fa = __half22float2(ha[j]);   // folds into v_fma_mix_f32
                const float2 fb = __half22float2(hb[j]);
                acc[2 * j]         = fmaf(fa.x, wk, acc[2 * j]);
                acc[2 * j + 1]     = fmaf(fa.y, wk, acc[2 * j + 1]);
                acc[2 * j + 4]     = fmaf(fb.x, wk, acc[2 * j + 4]);
                acc[2 * j + 5]     = fmaf(fb.y, wk, acc[2 * j + 5]);
            }
        }

        // sigmoid via v_rcp_f32 (~1 ulp) instead of the ~10-instr exact divide
        #pragma unroll
        for (int r = 0; r < R; ++r)
            acc[r] = __builtin_amdgcn_rcpf(1.0f + __expf(-acc[r]));

        if (l < LAYERS - 1) {
            __half2 pa[2], pb[2];
            #pragma unroll
            for (int j = 0; j < 2; ++j) {
                pa[j] = __floats2half2_rn(acc[2 * j],     acc[2 * j + 1]);
                pb[j] = __floats2half2_rn(acc[2 * j + 4], acc[2 * j + 5]);
            }
            char* wbp = (char*)vals + (N_IN + l * H + tid) * 8;
            *(uint2*)wbp              = *(const uint2*)pa;
            *(uint2*)(wbp + HALF_OFS) = *(const uint2*)pb;
            __syncthreads();
            // rotate prefetched params in (full unroll -> register renaming)
            #pragma unroll
            for (int k = 0; k < K; ++k) { idxA[k] = idxB[k]; wA[k] = wB[k]; }
            bA = bB;
        } else {
            // final layer: coalesced fp32 stores (lanes -> consecutive h)
            #pragma unroll
            for (int r = 0; r < R; ++r)
                out[(row0 + r) * H + tid] = acc[r];
        }
    }
}

extern "C" void kernel_launch(void* const* d_in, const int* in_sizes, int n_in,
                              void* d_out, int out_size, void* d_ws, size_t ws_size,
                              hipStream_t stream) {
    const float* x        = (const float*)d_in[0];
    const int*   link_idx = (const int*)  d_in[1];
    const float* weights  = (const float*)d_in[2];
    const float* bias     = (const float*)d_in[3];
    float*       out      = (float*)d_out;

    ffn_fused_kernel<<<dim3(BATCH / R), dim3(NT), 0, stream>>>(x, link_idx, weights, bias, out);
}